// Round 4
// baseline (160.796 us; speedup 1.0000x reference)
//
#include <hip/hip_runtime.h>
#include <hip/hip_bf16.h>

namespace {

constexpr int kN = 64, kC = 128, kT = 128, kV = 25, kH = 8, kc = 16;
constexpr int kKS = 13;            // K-steps of 32 (K' = 16 c * 26 = 416 = 13*32)
constexpr int kBCol = 448;         // output cols padded 400 -> 448 = 4 waves * 7 tiles * 16
constexpr int kBStep = kBCol * 32; // 14336 shorts per B k-slab (28672 B)
constexpr int kXRow = 424;         // shorts per A-tile row (848 B: 16B-aligned, bank-uniform)

typedef __attribute__((ext_vector_type(8))) short bf16x8;
typedef __attribute__((ext_vector_type(8))) unsigned short u16x8;
typedef __attribute__((ext_vector_type(4))) float f32x4;

__device__ inline unsigned short f2bf(float f) {
    unsigned int u = __builtin_bit_cast(unsigned int, f);
    u += 0x7fffu + ((u >> 16) & 1u);   // round-to-nearest-even
    return (unsigned short)(u >> 16);
}

__device__ inline float bf2f(unsigned short s) {
    return __builtin_bit_cast(float, ((unsigned int)s) << 16);
}

__device__ inline void glds16(const void* g, void* l) {
    __builtin_amdgcn_global_load_lds(
        (const __attribute__((address_space(1))) void*)g,
        (__attribute__((address_space(3))) void*)l, 16, 0, 0);
}
__device__ inline void glds4(const void* g, void* l) {
    __builtin_amdgcn_global_load_lds(
        (const __attribute__((address_space(1))) void*)g,
        (__attribute__((address_space(3))) void*)l, 4, 0, 0);
}

#define VMWAIT(n) do { asm volatile("s_waitcnt vmcnt(" #n ")" ::: "memory"); \
                       __builtin_amdgcn_sched_barrier(0); } while (0)
#define LGKM0     do { asm volatile("s_waitcnt lgkmcnt(0)" ::: "memory"); \
                       __builtin_amdgcn_sched_barrier(0); } while (0)
#define BAR()     __builtin_amdgcn_s_barrier()

// ---------------- P1: w1_i[h][v][w] = fc1/||.|| + pe/||.||  (norm over v) ----
__global__ void precompute_w1(const float* __restrict__ fc1,
                              const float* __restrict__ rpe,
                              const int* __restrict__ hops,
                              float* __restrict__ W1) {
    int ih = blockIdx.x;        // i*8+h, 0..23
    int w = threadIdx.x;
    if (w >= kV) return;
    const float* f = fc1 + ih * kV * kV;
    const float* r = rpe + ih * kV;
    float s1 = 0.f, s2 = 0.f;
    for (int v = 0; v < kV; ++v) {
        float a = f[v * kV + w];
        float p = r[hops[v * kV + w]];
        s1 += a * a; s2 += p * p;
    }
    float n1 = sqrtf(s1) + 1e-4f, n2 = sqrtf(s2) + 1e-4f;
    float* o = W1 + ih * kV * kV;
    for (int v = 0; v < kV; ++v) {
        float a = f[v * kV + w];
        float p = r[hops[v * kV + w]];
        o[v * kV + w] = a / n1 + p / n2;
    }
}

// ---------------- P2: combined weight, K-packed staging layout ---------------
// Wt3[h][k(13)][col(448)][lh(4)][j(8)] bf16.  kappa = k*32 + lh*8 + j;
// c = kappa/26, vv = kappa%26 (vv==25 -> zero K-row); col<400: d=col/25,w=col%25
// element = sum_i wg_i[h,d,c] * w1_i[h, v=vv, w]
__global__ void precompute_W(const float* __restrict__ W1,
                             const float* __restrict__ fc2_w,
                             unsigned short* __restrict__ Wt3) {
    int k = blockIdx.x;   // 0..12
    int h = blockIdx.y;   // 0..7
    unsigned short* outp = Wt3 + ((size_t)h * kKS + k) * kBStep;
    for (int e = threadIdx.x; e < kBStep; e += 256) {
        int col = e >> 5, lo = e & 31;
        int kap = k * 32 + lo;
        int c = kap / 26, vv = kap - c * 26;
        float val = 0.f;
        if (vv < 25 && col < 400) {
            int d = col / 25, w = col - d * 25;
            #pragma unroll
            for (int i = 0; i < 3; ++i) {
                float wg = fc2_w[(i * kC + h * kc + d) * kc + c];
                float w1 = W1[((i * kH + h) * kV + vv) * kV + w];
                val += wg * w1;
            }
        }
        outp[e] = f2bf(val);
    }
}

// ---------------- A: y = x * W  (x-stationary K-packed MFMA GEMM) ------------
// block = 64 rows (t-half of one n) x 448 cols (all), one h. 4 waves, each
// wave: all 64 rows (rf=4) x 7 col-tiles. x converted once into LDS A-tile;
// B double-buffered via glds with counted vmcnt (prefetch stays in flight).
__global__ __launch_bounds__(256, 1) void gemm_y(const float* __restrict__ x,
                                                 const unsigned short* __restrict__ Wt3,
                                                 unsigned short* __restrict__ yb) {
    __shared__ __align__(16) unsigned short Xl[64 * kXRow];   // 54272 B
    __shared__ __align__(16) unsigned short Bl[2][kBStep];    // 57344 B

    const int n = blockIdx.x, tb = blockIdx.y, h = blockIdx.z;
    const int tid = threadIdx.x, lane = tid & 63, wv = tid >> 6;
    const int ll = lane & 15, lh = lane >> 4;
    const int t0 = tb * 64;

    const float* xbase = x + ((size_t)(n * kC + h * kc) * kT + t0) * kV;
    const unsigned short* bbase = Wt3 + (size_t)h * kKS * kBStep;

    // stage 4 channels (6400 fp32, 4 runs of 64t*25v) into bounce = Bl[buf]
    auto stage_x = [&](int s, int buf) {
        float* bb = (float*)&Bl[buf][0];
        const float* src0 = xbase + (size_t)(s * 4) * (kT * kV);
        #pragma unroll
        for (int q = 0; q < 25; ++q) {
            int e = q * 256 + tid;
            int c = e / 1600, off = e - c * 1600;
            glds4(src0 + (size_t)c * (kT * kV) + off, bb + e);
        }
    };
    // thread = (cl=tid&3, t=tid>>2): 25 fp32 -> 13 packed bf16x2 writes
    auto convert = [&](int s, int buf) {
        const float* bp = (const float*)&Bl[buf][0] + (tid & 3) * 1600 + (tid >> 2) * 25;
        unsigned int* xw = (unsigned int*)&Xl[(size_t)(tid >> 2) * kXRow + (s * 4 + (tid & 3)) * 26];
        #pragma unroll
        for (int p = 0; p < 13; ++p) {
            float f0 = bp[2 * p];
            float f1 = (p < 12) ? bp[2 * p + 1] : 0.f;   // kappa%26==25 pad -> 0
            xw[p] = (unsigned)f2bf(f0) | ((unsigned)f2bf(f1) << 16);
        }
    };
    auto stage_b = [&](int k, int buf) {
        const unsigned short* src = bbase + (size_t)k * kBStep;
        unsigned short* dst = &Bl[buf][0];
        #pragma unroll
        for (int q = 0; q < 7; ++q)
            glds16(src + (size_t)(q * 256 + tid) * 8, dst + (size_t)(q * 256 + tid) * 8);
    };

    // ---- prologue: convert x into Xl, pipelined through the two B buffers ---
    stage_x(0, 0); stage_x(1, 1);        // out: 50
    VMWAIT(25); BAR();                    // S0 landed (all waves)
    convert(0, 0);
    LGKM0; BAR();                         // Bl[0] free
    stage_x(2, 0);                        // out: <=50
    VMWAIT(25); BAR();                    // S1 landed
    convert(1, 1);
    LGKM0; BAR();
    stage_x(3, 1);
    VMWAIT(25); BAR();                    // S2 landed
    convert(2, 0);
    LGKM0; BAR();
    stage_b(0, 0);                        // first B tile -> Bl[0]
    VMWAIT(7); BAR();                     // S3 landed (B0 may stay in flight)
    convert(3, 1);
    LGKM0; BAR();

    f32x4 acc[4][7];
    #pragma unroll
    for (int a = 0; a < 4; ++a)
        #pragma unroll
        for (int b = 0; b < 7; ++b) acc[a][b] = (f32x4)(0.f);

    // ---- main loop: 13 K-steps, B dbuf, counted vmcnt --------------------
    for (int k = 0; k < kKS; ++k) {
        const int cur = k & 1;
        if (k < kKS - 1) {
            stage_b(k + 1, cur ^ 1);      // prefetch stays in flight past barriers
            VMWAIT(7);                     // B_k landed (own wave)
        } else {
            VMWAIT(0);
        }
        BAR();                             // all waves' B_k landed

        bf16x8 af0 = *(const bf16x8*)&Xl[(size_t)((0 * 16 + ll) * kXRow) + k * 32 + lh * 8];
        bf16x8 af1 = *(const bf16x8*)&Xl[(size_t)((1 * 16 + ll) * kXRow) + k * 32 + lh * 8];
        bf16x8 af2 = *(const bf16x8*)&Xl[(size_t)((2 * 16 + ll) * kXRow) + k * 32 + lh * 8];
        bf16x8 af3 = *(const bf16x8*)&Xl[(size_t)((3 * 16 + ll) * kXRow) + k * 32 + lh * 8];
        #pragma unroll
        for (int ci = 0; ci < 7; ++ci) {
            bf16x8 bf = *(const bf16x8*)&Bl[cur][(size_t)(((wv * 7 + ci) * 16 + ll) * 32) + lh * 8];
            acc[0][ci] = __builtin_amdgcn_mfma_f32_16x16x32_bf16(af0, bf, acc[0][ci], 0, 0, 0);
            acc[1][ci] = __builtin_amdgcn_mfma_f32_16x16x32_bf16(af1, bf, acc[1][ci], 0, 0, 0);
            acc[2][ci] = __builtin_amdgcn_mfma_f32_16x16x32_bf16(af2, bf, acc[2][ci], 0, 0, 0);
            acc[3][ci] = __builtin_amdgcn_mfma_f32_16x16x32_bf16(af3, bf, acc[3][ci], 0, 0, 0);
        }
        BAR();                             // all waves done reading Bl[cur]
    }

    // ---- epilogue: D map col=lane&15, row=(lane>>4)*4+reg; store bf16 -------
    #pragma unroll
    for (int rf = 0; rf < 4; ++rf) {
        int t = t0 + rf * 16 + lh * 4;
        #pragma unroll
        for (int ci = 0; ci < 7; ++ci) {
            int m = (wv * 7 + ci) * 16 + ll;
            if (m < 400) {
                int d = m / 25, w = m - d * 25;
                unsigned short* yp = yb + ((size_t)(n * kC + h * kc + d) * kT + t) * kV + w;
                #pragma unroll
                for (int r = 0; r < 4; ++r)
                    yp[(size_t)r * kV] = f2bf(acc[rf][ci][r]);
            }
        }
    }
}

// ---------------- B1/B2: deterministic per-channel BN stats (bf16 y) ---------
__global__ void bn_partial(const unsigned short* __restrict__ yb,
                           float2* __restrict__ partials) {
    int g  = blockIdx.x;    // 0..7 (n-split)
    int ch = blockIdx.y;    // 0..127
    int tid = threadIdx.x;
    float s = 0.f, ss = 0.f;
    for (int n = g * 8; n < g * 8 + 8; ++n) {
        const u16x8* p = (const u16x8*)(yb + (size_t)(n * kC + ch) * (kT * kV));
        for (int e = tid; e < 400; e += 256) {
            u16x8 v = p[e];
            #pragma unroll
            for (int j = 0; j < 8; ++j) {
                float f = bf2f((unsigned short)v[j]);
                s += f; ss += f * f;
            }
        }
    }
    __shared__ float rs[256], rss[256];
    rs[tid] = s; rss[tid] = ss;
    __syncthreads();
    for (int o = 128; o > 0; o >>= 1) {
        if (tid < o) { rs[tid] += rs[tid + o]; rss[tid] += rss[tid + o]; }
        __syncthreads();
    }
    if (tid == 0) partials[ch * 8 + g] = make_float2(rs[0], rss[0]);
}

__global__ void bn_finalize(const float2* __restrict__ partials,
                            const float* __restrict__ gamma,
                            const float* __restrict__ beta,
                            float2* __restrict__ scsh) {
    int ch = threadIdx.x;
    if (ch >= kC) return;
    float s = 0.f, ss = 0.f;
    for (int g = 0; g < 8; ++g) {
        float2 p = partials[ch * 8 + g];
        s += p.x; ss += p.y;
    }
    const float inv = 1.f / (float)(kN * kT * kV);
    float mean = s * inv;
    float var  = ss * inv - mean * mean;
    float sc = gamma[ch] * rsqrtf(var + 1e-5f);
    scsh[ch] = make_float2(sc, beta[ch] - mean * sc);
}

// ---------------- C: out = relu(y*scale + shift + x) -------------------------
__global__ void bn_apply(const unsigned short* __restrict__ yb,
                         const float* __restrict__ x,
                         const float2* __restrict__ scsh,
                         float* __restrict__ out) {
    const size_t total8 = (size_t)kN * kC * kT * kV / 8;   // 3,276,800
    for (size_t i = (size_t)blockIdx.x * blockDim.x + threadIdx.x; i < total8;
         i += (size_t)gridDim.x * blockDim.x) {
        int ch = (int)((i / 400) % kC);          // 400 u16x8 per (n,ch)
        float2 sc = scsh[ch];
        u16x8 yv = ((const u16x8*)yb)[i];
        f32x4 x0 = ((const f32x4*)x)[i * 2];
        f32x4 x1 = ((const f32x4*)x)[i * 2 + 1];
        f32x4 o0, o1;
        #pragma unroll
        for (int q = 0; q < 4; ++q) {
            o0[q] = fmaxf(bf2f((unsigned short)yv[q]) * sc.x + sc.y + x0[q], 0.f);
            o1[q] = fmaxf(bf2f((unsigned short)yv[q + 4]) * sc.x + sc.y + x1[q], 0.f);
        }
        ((f32x4*)out)[i * 2]     = o0;
        ((f32x4*)out)[i * 2 + 1] = o1;
    }
}

} // namespace

extern "C" void kernel_launch(void* const* d_in, const int* in_sizes, int n_in,
                              void* d_out, int out_size, void* d_ws, size_t ws_size,
                              hipStream_t stream) {
    const float* x     = (const float*)d_in[0];
    const float* fc1   = (const float*)d_in[1];
    const float* rpe   = (const float*)d_in[2];
    const int*   hops  = (const int*)d_in[3];
    const float* fc2w  = (const float*)d_in[4];
    // d_in[5] = fc2_b: constant over BN reduction axes -> cancelled by BN.
    const float* gamma = (const float*)d_in[6];
    const float* beta  = (const float*)d_in[7];
    float* out = (float*)d_out;

    char* ws = (char*)d_ws;
    unsigned short* yb       = (unsigned short*)ws;                  // 52,428,800 B
    float*          W1       = (float*)(ws + 52428800);              // 60,000 B
    unsigned short* Wt3      = (unsigned short*)(ws + 52494336);     // 8*13*28672 = 2,981,888 B
    float2*         partials = (float2*)(ws + 55476224);             // 8,192 B
    float2*         scsh     = (float2*)(ws + 55484416);             // 1,024 B

    precompute_w1<<<24, 32, 0, stream>>>(fc1, rpe, hops, W1);
    precompute_W<<<dim3(13, 8), 256, 0, stream>>>(W1, fc2w, Wt3);
    gemm_y<<<dim3(64, 2, 8), 256, 0, stream>>>(x, Wt3, yb);
    bn_partial<<<dim3(8, 128), 256, 0, stream>>>(yb, partials);
    bn_finalize<<<1, 128, 0, stream>>>(partials, gamma, beta, scsh);
    bn_apply<<<2048, 256, 0, stream>>>(yb, x, scsh, out);
}

// Round 5
// 131.267 us; speedup vs baseline: 1.2250x; 1.2250x over previous
//
#include <hip/hip_runtime.h>
#include <hip/hip_bf16.h>

namespace {

constexpr int kN = 64, kC = 128, kT = 128, kV = 25, kH = 8, kc = 16;
constexpr int kKS = 13;             // K-steps of 32 (K' = 16c * 26 = 416)
constexpr int kBCol = 448;          // output cols padded 400 -> 448
constexpr int kBStep = kBCol * 32;  // 14336 shorts per B k-slab (28672 B)
constexpr int kXRow = 416;          // A-tile row stride in shorts (832 B)

typedef __attribute__((ext_vector_type(8))) short bf16x8;
typedef __attribute__((ext_vector_type(8))) unsigned short u16x8;
typedef __attribute__((ext_vector_type(4))) float f32x4;

__device__ inline unsigned short f2bf(float f) {
    unsigned int u = __builtin_bit_cast(unsigned int, f);
    u += 0x7fffu + ((u >> 16) & 1u);   // round-to-nearest-even
    return (unsigned short)(u >> 16);
}
__device__ inline float bf2f(unsigned short s) {
    return __builtin_bit_cast(float, ((unsigned int)s) << 16);
}
__device__ inline void glds16(const void* g, void* l) {
    __builtin_amdgcn_global_load_lds(
        (const __attribute__((address_space(1))) void*)g,
        (__attribute__((address_space(3))) void*)l, 16, 0, 0);
}

#define VMWAIT0() do { asm volatile("s_waitcnt vmcnt(0)" ::: "memory"); \
                       __builtin_amdgcn_sched_barrier(0); } while (0)
#define LGKM0()   do { asm volatile("s_waitcnt lgkmcnt(0)" ::: "memory"); \
                       __builtin_amdgcn_sched_barrier(0); } while (0)
#define BAR()     __builtin_amdgcn_s_barrier()

// ---------------- P1: w1_i[h][v][w] = fc1/||.|| + pe/||.||  (norm over v) ----
__global__ void precompute_w1(const float* __restrict__ fc1,
                              const float* __restrict__ rpe,
                              const int* __restrict__ hops,
                              float* __restrict__ W1) {
    int ih = blockIdx.x;        // i*8+h, 0..23
    int w = threadIdx.x;
    if (w >= kV) return;
    const float* f = fc1 + ih * kV * kV;
    const float* r = rpe + ih * kV;
    float s1 = 0.f, s2 = 0.f;
    for (int v = 0; v < kV; ++v) {
        float a = f[v * kV + w];
        float p = r[hops[v * kV + w]];
        s1 += a * a; s2 += p * p;
    }
    float n1 = sqrtf(s1) + 1e-4f, n2 = sqrtf(s2) + 1e-4f;
    float* o = W1 + ih * kV * kV;
    for (int v = 0; v < kV; ++v) {
        float a = f[v * kV + w];
        float p = r[hops[v * kV + w]];
        o[v * kV + w] = a / n1 + p / n2;
    }
}

// ---------------- P2: combined weight, K-packed staging layout ---------------
// Wt3[h][k(13)][col(448)][lh(4)][j(8)] bf16.  kappa = k*32 + lh*8 + j;
// c = kappa/26, vv = kappa%26 (vv==25 -> zero); col<400: d=col/25, w=col%25
__global__ void precompute_W(const float* __restrict__ W1,
                             const float* __restrict__ fc2_w,
                             unsigned short* __restrict__ Wt3) {
    int k = blockIdx.x;   // 0..12
    int h = blockIdx.y;   // 0..7
    unsigned short* outp = Wt3 + ((size_t)h * kKS + k) * kBStep;
    for (int e = threadIdx.x; e < kBStep; e += 256) {
        int col = e >> 5, lo = e & 31;
        int kap = k * 32 + lo;
        int c = kap / 26, vv = kap - c * 26;
        float val = 0.f;
        if (vv < 25 && col < 400) {
            int d = col / 25, w = col - d * 25;
            #pragma unroll
            for (int i = 0; i < 3; ++i) {
                float wg = fc2_w[(i * kC + h * kc + d) * kc + c];
                float w1 = W1[((i * kH + h) * kV + vv) * kV + w];
                val += wg * w1;
            }
        }
        outp[e] = f2bf(val);
    }
}

// ---------------- A: y = x*W, x-stationary, single-buffer B, reg fragments ---
// block = 64 rows (t-half of one n) x 448 cols, one h. 4 waves, each wave:
// all 64 rows (rf=4) x 7 col-tiles. LDS = Xl 53,248 + Bl 28,672 = 81,920 B
// -> exactly 2 blocks/CU. BN partial stats fused into epilogue.
__global__ __launch_bounds__(256, 2) void gemm_y(const float* __restrict__ x,
                                                 const unsigned short* __restrict__ Wt3,
                                                 unsigned short* __restrict__ yb,
                                                 float2* __restrict__ Pbuf) {
    __shared__ __align__(16) unsigned short Xl[64 * kXRow];  // 53,248 B
    __shared__ __align__(16) unsigned short Bl[kBStep];      // 28,672 B

    const int tb = blockIdx.x, n = blockIdx.y, h = blockIdx.z;
    const int tid = threadIdx.x, lane = tid & 63, wv = tid >> 6;
    const int ll = lane & 15, lh = lane >> 4;
    const int t0 = tb * 64;

    const float* xbase = x + ((size_t)(n * kC + h * kc) * kT + t0) * kV;  // c-stride 3200
    const unsigned short* bbase = Wt3 + (size_t)h * kKS * kBStep;
    float* Blf = (float*)&Bl[0];

    auto stage_x = [&](int s) {      // 4 c-slabs of 1600 fp32 -> bounce (=Bl)
        #pragma unroll
        for (int q = 0; q < 7; ++q) {
            int e = q * 256 + tid;
            if (e < 1600) {
                int c = e / 400, off = e - c * 400;
                glds16(xbase + (size_t)(s * 4 + c) * 3200 + off * 4,
                       (char*)Bl + (size_t)e * 16);
            }
        }
    };
    auto stage_b = [&](int k) {      // 1792 16B chunks = 7/thread, exact
        const unsigned short* src = bbase + (size_t)k * kBStep;
        #pragma unroll
        for (int q = 0; q < 7; ++q) {
            int e = q * 256 + tid;
            glds16(src + (size_t)e * 8, Bl + (size_t)e * 8);
        }
    };
    // wave wv converts slab c=4s+wv; lane t: 25 fp32 -> 13 dwords, rotated order
    auto convert = [&](int s) {
        const int t = lane;
        const int t13 = t % 13;
        const float* bp = Blf + wv * 1600 + t * 25;
        unsigned int* xw = (unsigned int*)&Xl[0] + t * (kXRow / 2) + (s * 4 + wv) * 13;
        #pragma unroll
        for (int i = 0; i < 13; ++i) {
            int p = i + t13; if (p >= 13) p -= 13;
            float f0 = bp[2 * p];
            float f1 = (p < 12) ? bp[2 * p + 1] : 0.f;   // kappa%26==25 pad
            xw[p] = (unsigned)f2bf(f0) | ((unsigned)f2bf(f1) << 16);
        }
    };

    // ---- prologue: convert x into Xl through Bl bounce (4 rounds) -----------
    #pragma unroll 1
    for (int s = 0; s < 4; ++s) {
        stage_x(s);
        VMWAIT0(); BAR();            // slab landed (all waves)
        convert(s);
        LGKM0(); BAR();              // all reads of bounce done -> Bl free
    }
    stage_b(0);

    f32x4 acc[4][7];
    #pragma unroll
    for (int a = 0; a < 4; ++a)
        #pragma unroll
        for (int b = 0; b < 7; ++b) acc[a][b] = (f32x4)(0.f);

    // ---- main loop: 13 K-steps, single-buffer B, frags in regs --------------
    #pragma unroll 1
    for (int k = 0; k < kKS; ++k) {
        VMWAIT0();                   // own stage(k) glds landed
        BAR();                       // collective: Bl[k] complete everywhere

        bf16x8 a0 = *(const bf16x8*)&Xl[(size_t)(0 * 16 + ll) * kXRow + k * 32 + lh * 8];
        bf16x8 a1 = *(const bf16x8*)&Xl[(size_t)(1 * 16 + ll) * kXRow + k * 32 + lh * 8];
        bf16x8 a2 = *(const bf16x8*)&Xl[(size_t)(2 * 16 + ll) * kXRow + k * 32 + lh * 8];
        bf16x8 a3 = *(const bf16x8*)&Xl[(size_t)(3 * 16 + ll) * kXRow + k * 32 + lh * 8];
        bf16x8 b[7];
        #pragma unroll
        for (int ci = 0; ci < 7; ++ci)
            b[ci] = *(const bf16x8*)&Bl[(size_t)((wv * 7 + ci) * 16 + ll) * 32 + lh * 8];

        LGKM0(); BAR();              // all waves' reads in regs -> Bl reusable
        if (k < kKS - 1) stage_b(k + 1);   // prefetch flies under MFMA

        #pragma unroll
        for (int ci = 0; ci < 7; ++ci) {
            acc[0][ci] = __builtin_amdgcn_mfma_f32_16x16x32_bf16(a0, b[ci], acc[0][ci], 0, 0, 0);
            acc[1][ci] = __builtin_amdgcn_mfma_f32_16x16x32_bf16(a1, b[ci], acc[1][ci], 0, 0, 0);
            acc[2][ci] = __builtin_amdgcn_mfma_f32_16x16x32_bf16(a2, b[ci], acc[2][ci], 0, 0, 0);
            acc[3][ci] = __builtin_amdgcn_mfma_f32_16x16x32_bf16(a3, b[ci], acc[3][ci], 0, 0, 0);
        }
    }

    // ---- epilogue: y store (D map col=ll, row=lh*4+r) + fused BN partials ---
    #pragma unroll
    for (int rf = 0; rf < 4; ++rf) {
        int t = t0 + rf * 16 + lh * 4;
        #pragma unroll
        for (int ci = 0; ci < 7; ++ci) {
            int m = wv * 112 + ci * 16 + ll;
            if (m < 400) {
                int d = m / 25, w = m - d * 25;
                unsigned short* yp = yb + ((size_t)(n * kC + h * kc + d) * kT + t) * kV + w;
                #pragma unroll
                for (int r = 0; r < 4; ++r)
                    yp[(size_t)r * kV] = f2bf(acc[rf][ci][r]);
            }
        }
    }

    float2* Bs = (float2*)&Bl[0];    // 448 float2 = 3584 B, loop is done with Bl
    #pragma unroll
    for (int ci = 0; ci < 7; ++ci) {
        float s = 0.f, ss = 0.f;
        #pragma unroll
        for (int rf = 0; rf < 4; ++rf)
            #pragma unroll
            for (int r = 0; r < 4; ++r) {
                float v = acc[rf][ci][r];
                s += v; ss += v * v;
            }
        s  += __shfl_xor(s, 16);  ss += __shfl_xor(ss, 16);
        s  += __shfl_xor(s, 32);  ss += __shfl_xor(ss, 32);
        if (lh == 0) Bs[wv * 112 + ci * 16 + ll] = make_float2(s, ss);
    }
    __syncthreads();
    if (tid < 16) {                  // per-channel-d partial over this block
        float s = 0.f, ss = 0.f;
        for (int w = 0; w < 25; ++w) {
            float2 p = Bs[tid * 25 + w];
            s += p.x; ss += p.y;
        }
        size_t bid = (size_t)tb + 2 * ((size_t)n + 64 * (size_t)h);
        Pbuf[bid * 16 + tid] = make_float2(s, ss);
    }
}

// ---------------- B2: finalize BN stats --------------------------------------
__global__ void bn_finalize(const float2* __restrict__ Pbuf,
                            const float* __restrict__ gamma,
                            const float* __restrict__ beta,
                            float2* __restrict__ scsh) {
    int ch = threadIdx.x;
    if (ch >= kC) return;
    int h = ch >> 4, d = ch & 15;
    float s = 0.f, ss = 0.f;
    for (int j = 0; j < 128; ++j) {          // j = tb + 2n
        float2 p = Pbuf[(size_t)(j + 128 * h) * 16 + d];
        s += p.x; ss += p.y;
    }
    const float inv = 1.f / (float)(kN * kT * kV);
    float mean = s * inv;
    float var  = ss * inv - mean * mean;
    float sc = gamma[ch] * rsqrtf(var + 1e-5f);
    scsh[ch] = make_float2(sc, beta[ch] - mean * sc);
}

// ---------------- C: out = relu(y*scale + shift + x) -------------------------
__global__ void bn_apply(const unsigned short* __restrict__ yb,
                         const float* __restrict__ x,
                         const float2* __restrict__ scsh,
                         float* __restrict__ out) {
    const size_t total8 = (size_t)kN * kC * kT * kV / 8;   // 3,276,800
    for (size_t i = (size_t)blockIdx.x * blockDim.x + threadIdx.x; i < total8;
         i += (size_t)gridDim.x * blockDim.x) {
        int ch = (int)((i / 400) % kC);          // 400 u16x8 per (n,ch)
        float2 sc = scsh[ch];
        u16x8 yv = ((const u16x8*)yb)[i];
        f32x4 x0 = ((const f32x4*)x)[i * 2];
        f32x4 x1 = ((const f32x4*)x)[i * 2 + 1];
        f32x4 o0, o1;
        #pragma unroll
        for (int q = 0; q < 4; ++q) {
            o0[q] = fmaxf(bf2f((unsigned short)yv[q]) * sc.x + sc.y + x0[q], 0.f);
            o1[q] = fmaxf(bf2f((unsigned short)yv[q + 4]) * sc.x + sc.y + x1[q], 0.f);
        }
        ((f32x4*)out)[i * 2]     = o0;
        ((f32x4*)out)[i * 2 + 1] = o1;
    }
}

} // namespace

extern "C" void kernel_launch(void* const* d_in, const int* in_sizes, int n_in,
                              void* d_out, int out_size, void* d_ws, size_t ws_size,
                              hipStream_t stream) {
    const float* x     = (const float*)d_in[0];
    const float* fc1   = (const float*)d_in[1];
    const float* rpe   = (const float*)d_in[2];
    const int*   hops  = (const int*)d_in[3];
    const float* fc2w  = (const float*)d_in[4];
    // d_in[5] = fc2_b: constant over BN reduction axes -> cancelled by BN.
    const float* gamma = (const float*)d_in[6];
    const float* beta  = (const float*)d_in[7];
    float* out = (float*)d_out;

    char* ws = (char*)d_ws;
    unsigned short* yb   = (unsigned short*)ws;                  // 52,428,800 B
    float*          W1   = (float*)(ws + 52428800);              // 60,000 B (pad 64K)
    unsigned short* Wt3  = (unsigned short*)(ws + 52494336);     // 2,981,888 B
    float2*         Pbuf = (float2*)(ws + 55476224);             // 131,072 B
    float2*         scsh = (float2*)(ws + 55607296);             // 1,024 B

    precompute_w1<<<24, 32, 0, stream>>>(fc1, rpe, hops, W1);
    precompute_W<<<dim3(13, 8), 256, 0, stream>>>(W1, fc2w, Wt3);
    gemm_y<<<dim3(2, 64, 8), 256, 0, stream>>>(x, Wt3, yb, Pbuf);
    bn_finalize<<<1, 128, 0, stream>>>(Pbuf, gamma, beta, scsh);
    bn_apply<<<2048, 256, 0, stream>>>(yb, x, scsh, out);
}